// Round 1
// 1985.075 us; speedup vs baseline: 1.0101x; 1.0101x over previous
//
#include <hip/hip_runtime.h>
#include <stdint.h>

// ContTimeLSTM: B=128, L=512, I=256, D=512.
// Round 7: self-tagged h exchange. Each h element is stored as one dword
// (tag=t+1)<<16 | bf16(h) with sc0 sc1 (LLC write-through). Consumers poll the
// DATA dwords directly until all tags match -> no flags, no vmcnt(0) drain, no
// flag-visibility round trip, and the successful poll IS the h load. Removes
// ~2 serialized LLC round trips + 1 barrier per step vs round 6.
constexpr int B_   = 128;
constexpr int L_   = 512;
constexpr int I_   = 256;
constexpr int D_   = 512;
constexpr int KTOT = I_ + D_;     // 768
constexpr int ND7  = 7 * D_;      // 3584
constexpr int RW   = 16;          // rows per workgroup
constexpr int MW   = 16;          // m (state dim) per workgroup
constexpr int RG   = B_ / RW;     // 8 row groups (rg = bid & 7 -> XCD-local)
constexpr int MG   = D_ / MW;     // 32 m groups
constexpr int NWG  = RG * MG;     // 256 workgroups (1 per CU)
constexpr int NTHR = 256;         // 4 waves
constexpr int PS   = 122;         // padded LDS row stride (floats)

typedef short  bfrag8 __attribute__((ext_vector_type(8)));  // 8 bf16 (4 VGPRs)
typedef float  f32x4  __attribute__((ext_vector_type(4)));
typedef int    i32x4  __attribute__((ext_vector_type(4)));

__device__ __forceinline__ unsigned short f2bf(float f) {
    union { float f; uint32_t i; } v; v.f = f;
    uint32_t x = v.i;
    return (unsigned short)((x + 0x7fffu + ((x >> 16) & 1u)) >> 16);  // RNE
}
__device__ __forceinline__ bfrag8 pack8(float4 a, float4 b) {
    bfrag8 r;
    r[0] = (short)f2bf(a.x); r[1] = (short)f2bf(a.y);
    r[2] = (short)f2bf(a.z); r[3] = (short)f2bf(a.w);
    r[4] = (short)f2bf(b.x); r[5] = (short)f2bf(b.y);
    r[6] = (short)f2bf(b.z); r[7] = (short)f2bf(b.w);
    return r;
}
__device__ __forceinline__ float sigm(float x) { return 1.0f / (1.0f + __expf(-x)); }
__device__ __forceinline__ float tanh_f(float x) {
    float xc = fminf(fmaxf(x, -15.f), 15.f);
    float e  = __expf(2.f * xc);
    return (e - 1.f) / (e + 1.f);
}
__device__ __forceinline__ float softplus_f(float x) {
    return (x > 15.f) ? x : log1pf(__expf(x));
}

// LLC-coherent write-through dword store (bypasses/doesn't dirty L1+L2).
__device__ __forceinline__ void store_llc_u32(uint32_t* p, uint32_t v) {
    asm volatile("global_store_dword %0, %1, off sc0 sc1"
                 :: "v"(p), "v"(v) : "memory");
}

// Pack low 16 bits (the h bf16) of 8 tagged dwords into one bfrag8.
__device__ __forceinline__ bfrag8 unpack_lo16(i32x4 a, i32x4 b) {
    union { int i[4]; bfrag8 f; } u;
    u.i[0] = (int)__builtin_amdgcn_perm((uint32_t)a[1], (uint32_t)a[0], 0x05040100u);
    u.i[1] = (int)__builtin_amdgcn_perm((uint32_t)a[3], (uint32_t)a[2], 0x05040100u);
    u.i[2] = (int)__builtin_amdgcn_perm((uint32_t)b[1], (uint32_t)b[0], 0x05040100u);
    u.i[3] = (int)__builtin_amdgcn_perm((uint32_t)b[3], (uint32_t)b[2], 0x05040100u);
    return u.f;
}

// Prologue: proj0[j] = dot(W[j, 0:I], bos) + bias[j]  (BOS step, zero state)
__global__ void bos_proj_kernel(const float* __restrict__ W,
                                const float* __restrict__ bos,
                                const float* __restrict__ bias,
                                float* __restrict__ proj0) {
    int j = blockIdx.x * blockDim.x + threadIdx.x;
    if (j >= ND7) return;
    const float* wr = W + (size_t)j * KTOT;
    float s = 0.f;
#pragma unroll 8
    for (int k = 0; k < I_; ++k) s += wr[k] * bos[k];
    proj0[j] = s + bias[j];
}

// Persistent recurrence kernel.
// WG (rg,mg): rows b0..b0+15, state dims m0..m0+15, proj cols {g*512+m0+0..15}.
// Weights pinned in VGPRs (bf16): wave w holds K-steps s = w+4i (i=0..5), 7 N-tiles.
// Sync: NONE beyond the self-tagged dwords. Producer stores (t+1)<<16|bf16(h)
// per element; each wave independently polls its own 32 dwords until all tags
// match, then uses them directly as MFMA A-fragments. Ping-pong (2 slots)
// makes the overwrite-at-t+2 safe (transitive data dependence through the
// full-K projection).
__global__ void __launch_bounds__(NTHR, 1)
ctlstm_kernel(const float* __restrict__ X,     // (B,L,I) f32
              const float* __restrict__ DT,    // (B,L)   f32
              const int*   __restrict__ SEQ,   // (B,)    int32
              const float* __restrict__ W,     // (7D, K) f32
              const float* __restrict__ BIAS,  // (7D,)   f32
              const float* __restrict__ PROJ0, // (7D,)   f32
              uint32_t* __restrict__ HBUF,     // (2,B,D) tagged dwords (LLC)
              float* __restrict__ OUT)         // f32: outputs (B,L,D) | final (B,4D)
{
    __shared__ float lds[4 * RW * PS];

    const int tid  = threadIdx.x;
    const int wid  = tid >> 6;      // wave 0..3
    const int lane = tid & 63;
    const int bid  = blockIdx.x;
    const int rg   = bid & 7;       // row group (XCD-local under round-robin)
    const int mg   = bid >> 3;      // m group
    const int b0   = rg * RW;
    const int m0   = mg * MW;

    // elementwise mapping: thread <-> (row, mi)
    const int erow = tid >> 4;
    const int emi  = tid & 15;
    const int eb   = b0 + erow;
    const int em   = m0 + emi;
    const int esl  = SEQ[eb];

    // MFMA lane mapping
    const int lrow = lane & 15;     // A row (batch) / B,C col
    const int lq   = lane >> 4;     // quad -> k-octet / C row block
    const int lb   = b0 + lrow;
    const int lsl  = SEQ[lb];
    const int kb   = wid * 32 + lq * 8;   // h-k base for this lane's fragments

    // ---- pin B fragments (weights, f32 -> bf16 RNE): Bf[i][g], K-step s=wid+4i
    bfrag8 Bf[6][7];
#pragma unroll
    for (int i = 0; i < 6; ++i) {
        const int s = wid + 4 * i;
        const int k = s * 32 + lq * 8;
#pragma unroll
        for (int g = 0; g < 7; ++g) {
            const int j = g * D_ + m0 + lrow;       // proj column
            const float4* wp = (const float4*)(W + (size_t)j * KTOT + k);
            Bf[i][g] = pack8(wp[0], wp[1]);
        }
    }

    // bias per elementwise thread (f32)
    float bg[7];
#pragma unroll
    for (int g = 0; g < 7; ++g) bg[g] = BIAS[g * D_ + em];

    // ---- initial state from BOS projection (same for every batch row)
    float p0[7];
#pragma unroll
    for (int g = 0; g < 7; ++g) p0[g] = PROJ0[g * D_ + em];
    float z0  = tanh_f(p0[5]);
    float so  = sigm(p0[4]);          // o
    float scs = sigm(p0[0]) * z0;     // cs = i*z  (c=0)
    float sce = sigm(p0[2]) * z0;     // ce = ie*z (ce=0)
    float sd  = softplus_f(p0[6]);    // d

    const size_t OUTF = (size_t)B_ * L_ * D_;   // final-state offset (f32 elems)

    // ---- prologue prefetch (t=0 always < seq_len since seq_len >= L/2)
    float dtc = DT[(size_t)eb * L_];
    bfrag8 ax[2];
#pragma unroll
    for (int i = 0; i < 2; ++i) {
        const int k = (wid + 4 * i) * 32 + lq * 8;
        const float4* xp = (const float4*)(X + (size_t)lb * L_ * I_ + k);
        ax[i] = pack8(xp[0], xp[1]);
    }

    for (int t = 0; t < L_; ++t) {
        // ---- phase 1: decay + h (uses previous state; local)
        float c   = sce + (scs - sce) * __expf(-sd * dtc);
        float h   = so * tanh_f(c);

        // ---- tagged h -> LLC, fire-and-forget (one dword per element)
        const uint32_t tagv = ((uint32_t)(t + 1) << 16) | (uint32_t)f2bf(h);
        store_llc_u32(HBUF + ((size_t)(t & 1) * B_ + eb) * D_ + em, tagv);

        // ---- off-critical-path: f32 output store (cached, lazy writeback)
        OUT[((size_t)eb * L_ + t) * D_ + em] = h;

        // ---- x-part MFMAs (fragments prefetched last step)
        f32x4 acc[7];
#pragma unroll
        for (int g = 0; g < 7; ++g) acc[g] = (f32x4){0.f, 0.f, 0.f, 0.f};
#pragma unroll
        for (int i = 0; i < 2; ++i)
#pragma unroll
            for (int g = 0; g < 7; ++g)
                acc[g] = __builtin_amdgcn_mfma_f32_16x16x32_bf16(ax[i], Bf[i][g], acc[g], 0, 0, 0);

        // ---- prefetch next-step x fragments + dt (latency hides under poll)
        if (t + 1 < L_) {
            dtc = (t + 1 < esl) ? DT[(size_t)eb * L_ + t + 1] : 0.f;
#pragma unroll
            for (int i = 0; i < 2; ++i) {
                const int k = (wid + 4 * i) * 32 + lq * 8;
                float4 xa = {0.f,0.f,0.f,0.f}, xb = {0.f,0.f,0.f,0.f};
                if (t + 1 < lsl) {
                    const float4* xp = (const float4*)(X + ((size_t)lb * L_ + t + 1) * I_ + k);
                    xa = xp[0]; xb = xp[1];
                }
                ax[i] = pack8(xa, xb);
            }
        }

        // ---- poll the tagged h dwords (per-wave independent; poll IS the load)
        const uint32_t* hrow32 = HBUF + ((size_t)(t & 1) * B_ + lb) * D_ + kb;
        const uint32_t wh = (uint32_t)(t + 1) << 16;
        i32x4 q0, q1, q2, q3, q4, q5, q6, q7;
        while (true) {
            asm volatile(
                "global_load_dwordx4 %0, %8, off sc0 sc1\n\t"
                "global_load_dwordx4 %1, %8, off offset:16 sc0 sc1\n\t"
                "global_load_dwordx4 %2, %9, off sc0 sc1\n\t"
                "global_load_dwordx4 %3, %9, off offset:16 sc0 sc1\n\t"
                "global_load_dwordx4 %4, %10, off sc0 sc1\n\t"
                "global_load_dwordx4 %5, %10, off offset:16 sc0 sc1\n\t"
                "global_load_dwordx4 %6, %11, off sc0 sc1\n\t"
                "global_load_dwordx4 %7, %11, off offset:16 sc0 sc1\n\t"
                "s_waitcnt vmcnt(0)"
                : "=&v"(q0), "=&v"(q1), "=&v"(q2), "=&v"(q3),
                  "=&v"(q4), "=&v"(q5), "=&v"(q6), "=&v"(q7)
                : "v"(hrow32), "v"(hrow32 + 128), "v"(hrow32 + 256), "v"(hrow32 + 384)
                : "memory");
            uint32_t bad =
                ((uint32_t)q0[0] ^ wh) | ((uint32_t)q0[1] ^ wh) |
                ((uint32_t)q0[2] ^ wh) | ((uint32_t)q0[3] ^ wh);
            bad |= ((uint32_t)q1[0] ^ wh) | ((uint32_t)q1[1] ^ wh) |
                   ((uint32_t)q1[2] ^ wh) | ((uint32_t)q1[3] ^ wh);
            bad |= ((uint32_t)q2[0] ^ wh) | ((uint32_t)q2[1] ^ wh) |
                   ((uint32_t)q2[2] ^ wh) | ((uint32_t)q2[3] ^ wh);
            bad |= ((uint32_t)q3[0] ^ wh) | ((uint32_t)q3[1] ^ wh) |
                   ((uint32_t)q3[2] ^ wh) | ((uint32_t)q3[3] ^ wh);
            bad |= ((uint32_t)q4[0] ^ wh) | ((uint32_t)q4[1] ^ wh) |
                   ((uint32_t)q4[2] ^ wh) | ((uint32_t)q4[3] ^ wh);
            bad |= ((uint32_t)q5[0] ^ wh) | ((uint32_t)q5[1] ^ wh) |
                   ((uint32_t)q5[2] ^ wh) | ((uint32_t)q5[3] ^ wh);
            bad |= ((uint32_t)q6[0] ^ wh) | ((uint32_t)q6[1] ^ wh) |
                   ((uint32_t)q6[2] ^ wh) | ((uint32_t)q6[3] ^ wh);
            bad |= ((uint32_t)q7[0] ^ wh) | ((uint32_t)q7[1] ^ wh) |
                   ((uint32_t)q7[2] ^ wh) | ((uint32_t)q7[3] ^ wh);
            if (__all((int)((bad >> 16) == 0u))) break;
            __builtin_amdgcn_s_sleep(1);
        }

        // ---- strip tags -> A fragments, h-part MFMAs (K-steps s = 8..23)
        bfrag8 ah0 = unpack_lo16(q0, q1);
        bfrag8 ah1 = unpack_lo16(q2, q3);
        bfrag8 ah2 = unpack_lo16(q4, q5);
        bfrag8 ah3 = unpack_lo16(q6, q7);
#pragma unroll
        for (int g = 0; g < 7; ++g) {
            acc[g] = __builtin_amdgcn_mfma_f32_16x16x32_bf16(ah0, Bf[2][g], acc[g], 0, 0, 0);
            acc[g] = __builtin_amdgcn_mfma_f32_16x16x32_bf16(ah1, Bf[3][g], acc[g], 0, 0, 0);
            acc[g] = __builtin_amdgcn_mfma_f32_16x16x32_bf16(ah2, Bf[4][g], acc[g], 0, 0, 0);
            acc[g] = __builtin_amdgcn_mfma_f32_16x16x32_bf16(ah3, Bf[5][g], acc[g], 0, 0, 0);
        }

        // ---- cross-wave K-reduction via LDS
        __syncthreads();   // WAR: all waves done reading LDS from previous step
        // C/D layout: col = lane&15, row = (lane>>4)*4 + reg  (m89/m91)
#pragma unroll
        for (int g = 0; g < 7; ++g)
#pragma unroll
            for (int r = 0; r < 4; ++r)
                lds[(wid * RW + lq * 4 + r) * PS + g * 16 + lrow] = acc[g][r];

        __syncthreads();

        // ---- phase 4: gates + state update (local)
        float p[7];
#pragma unroll
        for (int g = 0; g < 7; ++g) {
            float s = bg[g];
#pragma unroll
            for (int w2 = 0; w2 < 4; ++w2)
                s += lds[(w2 * RW + erow) * PS + g * 16 + emi];
            p[g] = s;
        }
        float ig  = sigm(p[0]);
        float fg  = sigm(p[1]);
        float ieg = sigm(p[2]);
        float feg = sigm(p[3]);
        float on  = sigm(p[4]);
        float z   = tanh_f(p[5]);
        float dn  = softplus_f(p[6]);
        float csn = fg * c + ig * z;
        float cen = feg * sce + ieg * z;
        so = on; scs = csn; sce = cen; sd = dn;

        if (t == esl - 1) {   // capture final state (post-update) at seq_len-1
            size_t fo = OUTF + (size_t)eb * (4 * D_) + em;
            OUT[fo]          = on;
            OUT[fo + D_]     = csn;
            OUT[fo + 2 * D_] = cen;
            OUT[fo + 3 * D_] = dn;
        }
    }
}

extern "C" void kernel_launch(void* const* d_in, const int* in_sizes, int n_in,
                              void* d_out, int out_size, void* d_ws, size_t ws_size,
                              hipStream_t stream) {
    const float* X   = (const float*)d_in[0];
    const float* DT  = (const float*)d_in[1];
    const int*   SEQ = (const int*)d_in[2];
    const float* BOS = (const float*)d_in[3];
    const float* W   = (const float*)d_in[4];
    const float* BI  = (const float*)d_in[5];
    float*       OUT = (float*)d_out;

    float*    proj0 = (float*)d_ws;                            // 14336 B
    uint32_t* hbuf  = (uint32_t*)((char*)d_ws + 16384);        // 2*B*D dwords = 512 KB

    // tags must not alias any step's tag at launch (graph replay safe)
    hipMemsetAsync((char*)d_ws + 16384, 0, (size_t)2 * B_ * D_ * 4, stream);

    bos_proj_kernel<<<(ND7 + 255) / 256, 256, 0, stream>>>(W, BOS, BI, proj0);

    ctlstm_kernel<<<dim3(NWG), dim3(NTHR), 0, stream>>>(
        X, DT, SEQ, W, BI, proj0, hbuf, OUT);
}